// Round 6
// baseline (207.764 us; speedup 1.0000x reference)
//
#include <hip/hip_runtime.h>
#include <hip/hip_bf16.h>

// DIAGNOSTIC ROUND: kernels identical to R5, but each dispatch carries 3x
// replicated work (identical writes -> deterministic, output unchanged) so
// both kernels exceed the ~75us fill dispatches and surface in rocprof top-5
// with their counters. dur_us is sacrificial this round.
#define C_ 256
#define H_ 200
#define W_ 304
#define AH 7
#define AW 7
#define KK (AH * AW)
#define SP 260
#define REP 3

typedef float f32x4 __attribute__((ext_vector_type(4)));

__device__ __forceinline__ float b2f(unsigned short s) {
    return __uint_as_float((unsigned int)s << 16);
}

// ---------- Kernel 1: NCHW f32 -> NHWC bf16 (x-grid replicated x3) ----------
__global__ __launch_bounds__(256) void transpose_nchw_nhwc_bf16(
    const float* __restrict__ in, unsigned short* __restrict__ out) {
    __shared__ unsigned int tile[128][34];  // [ch][px-pair]
    const int HW = H_ * W_;
    const int n  = blockIdx.z;
    const int p0 = (blockIdx.x % (HW / 64)) * 64;  // replica-fold
    const int c0 = blockIdx.y * 128;
    const float* inb = in + (size_t)n * C_ * HW;
    unsigned short* outb = out + (size_t)n * HW * C_;

    {
        const int q  = threadIdx.x & 15;
        const int r0 = threadIdx.x >> 4;
        #pragma unroll
        for (int i = 0; i < 8; ++i) {
            const int c = r0 + 16 * i;
            const f32x4 v = __builtin_nontemporal_load(
                (const f32x4*)&inb[(size_t)(c0 + c) * HW + p0 + 4 * q]);
            const __hip_bfloat162 lo = __float22bfloat162_rn(make_float2(v.x, v.y));
            const __hip_bfloat162 hi = __float22bfloat162_rn(make_float2(v.z, v.w));
            unsigned int ulo, uhi;
            __builtin_memcpy(&ulo, &lo, 4);
            __builtin_memcpy(&uhi, &hi, 4);
            *(uint2*)&tile[c][2 * q] = make_uint2(ulo, uhi);
        }
    }
    __syncthreads();
    {
        const int pp0 = threadIdx.x & 15;
        const int cq  = threadIdx.x >> 4;
        #pragma unroll
        for (int i = 0; i < 2; ++i) {
            const int pp = pp0 + 16 * i;
            unsigned int u[8];
            #pragma unroll
            for (int j = 0; j < 8; ++j) u[j] = tile[8 * cq + j][pp];
            unsigned int pe[4], po[4];
            #pragma unroll
            for (int k = 0; k < 4; ++k) {
                pe[k] = (u[2 * k] & 0xFFFFu) | (u[2 * k + 1] << 16);
                po[k] = (u[2 * k] >> 16) | (u[2 * k + 1] & 0xFFFF0000u);
            }
            unsigned short* oA = &outb[(size_t)(p0 + 2 * pp) * C_ + c0 + 8 * cq];
            unsigned short* oB = oA + C_;
            *(uint4*)oA = make_uint4(pe[0], pe[1], pe[2], pe[3]);
            *(uint4*)oB = make_uint4(po[0], po[1], po[2], po[3]);
        }
    }
}

// ---------- Kernel 2: gather (y-grid replicated x3, replica ignored) ----------
__global__ __launch_bounds__(512) void roialign_nhwc_bf16(
    const unsigned short* __restrict__ tf, const float* __restrict__ rois,
    const float* __restrict__ scale_ptr, float* __restrict__ out) {
    __shared__ float sout[KK * SP];
    const int r    = blockIdx.x;
    const int wave = threadIdx.x >> 6;
    const int lane = threadIdx.x & 63;
    const int c4   = lane * 4;

    const float scale = scale_ptr[0];
    const float* roi = rois + (size_t)r * 5;
    const int   b  = (int)roi[0];
    const float x1 = roi[1] * scale;
    const float y1 = roi[2] * scale;
    const float x2 = roi[3] * scale;
    const float y2 = roi[4] * scale;
    const float roi_w = fmaxf(x2 - x1 + 1.0f, 0.0f);
    const float roi_h = fmaxf(y2 - y1 + 1.0f, 0.0f);
    const float bin_h = roi_h / (float)(AH - 1);
    const float bin_w = roi_w / (float)(AW - 1);
    const unsigned short* fb = tf + (size_t)b * (H_ * W_) * C_;

    #pragma unroll 2
    for (int k = wave; k < KK; k += 8) {
        const int ph = k / AW;
        const int pw = k - ph * AW;
        const float h  = y1 + (float)ph * bin_h;
        const float w  = x1 + (float)pw * bin_w;
        const float hs = fminf(fmaxf(floorf(h), 0.0f), (float)(H_ - 2));
        const float ws = fminf(fmaxf(floorf(w), 0.0f), (float)(W_ - 2));
        const float dh = h - hs;
        const float dw = w - ws;
        const int   yi = (int)hs;
        const int   xi = (int)ws;
        const bool  valid = (h >= 0.0f) && (h < (float)H_) &&
                            (w >= 0.0f) && (w < (float)W_);
        const unsigned short* p = fb + ((size_t)yi * W_ + xi) * C_ + c4;
        const ushort4 a00 = *(const ushort4*)p;
        const ushort4 a01 = *(const ushort4*)(p + C_);
        const ushort4 a10 = *(const ushort4*)(p + (size_t)W_ * C_);
        const ushort4 a11 = *(const ushort4*)(p + (size_t)W_ * C_ + C_);
        const float w00 = (1.0f - dh) * (1.0f - dw);
        const float w01 = (1.0f - dh) * dw;
        const float w10 = dh * (1.0f - dw);
        const float w11 = dh * dw;
        float4 v;
        v.x = b2f(a00.x) * w00 + b2f(a01.x) * w01 + b2f(a10.x) * w10 + b2f(a11.x) * w11;
        v.y = b2f(a00.y) * w00 + b2f(a01.y) * w01 + b2f(a10.y) * w10 + b2f(a11.y) * w11;
        v.z = b2f(a00.z) * w00 + b2f(a01.z) * w01 + b2f(a10.z) * w10 + b2f(a11.z) * w11;
        v.w = b2f(a00.w) * w00 + b2f(a01.w) * w01 + b2f(a10.w) * w10 + b2f(a11.w) * w11;
        if (!valid) { v.x = 0.0f; v.y = 0.0f; v.z = 0.0f; v.w = 0.0f; }
        *(float4*)&sout[k * SP + c4] = v;
    }
    __syncthreads();
    float* ob = out + (size_t)r * C_ * KK;
    const int nf4 = C_ * KK / 4;
    for (int idx = threadIdx.x; idx < nf4; idx += 512) {
        const int f = 4 * idx;
        f32x4 v;
        #pragma unroll
        for (int e = 0; e < 4; ++e) {
            const int fe = f + e;
            const int c = fe / KK;
            const int k = fe - c * KK;
            v[e] = sout[k * SP + c];
        }
        __builtin_nontemporal_store(v, (f32x4*)&ob[f]);
    }
}

// ---------- Fallback: direct NCHW gather (if ws too small) ----------
__global__ __launch_bounds__(256) void roialign_nchw(
    const float* __restrict__ feat, const float* __restrict__ rois,
    const float* __restrict__ scale_ptr, float* __restrict__ out) {
    __shared__ float sout[C_ * KK];
    const int r = blockIdx.x;
    const int c = threadIdx.x;
    const float scale = scale_ptr[0];
    const float* roi = rois + (size_t)r * 5;
    const int   b  = (int)roi[0];
    const float x1 = roi[1] * scale;
    const float y1 = roi[2] * scale;
    const float x2 = roi[3] * scale;
    const float y2 = roi[4] * scale;
    const float roi_w = fmaxf(x2 - x1 + 1.0f, 0.0f);
    const float roi_h = fmaxf(y2 - y1 + 1.0f, 0.0f);
    const float bin_h = roi_h / (float)(AH - 1);
    const float bin_w = roi_w / (float)(AW - 1);
    const float* fb = feat + ((size_t)b * C_ + c) * (H_ * W_);

    for (int ph = 0; ph < AH; ++ph) {
        const float h  = y1 + (float)ph * bin_h;
        const float hs = fminf(fmaxf(floorf(h), 0.0f), (float)(H_ - 2));
        const float dh = h - hs;
        const int   yi = (int)hs;
        const bool  vh = (h >= 0.0f) && (h < (float)H_);
        #pragma unroll
        for (int pw = 0; pw < AW; ++pw) {
            const float w  = x1 + (float)pw * bin_w;
            const float ws = fminf(fmaxf(floorf(w), 0.0f), (float)(W_ - 2));
            const float dw = w - ws;
            const int   xi = (int)ws;
            const bool  valid = vh && (w >= 0.0f) && (w < (float)W_);
            const float v00 = fb[(size_t)yi * W_ + xi];
            const float v01 = fb[(size_t)yi * W_ + xi + 1];
            const float v10 = fb[(size_t)(yi + 1) * W_ + xi];
            const float v11 = fb[(size_t)(yi + 1) * W_ + xi + 1];
            float val = v00 * (1.0f - dh) * (1.0f - dw)
                      + v01 * (1.0f - dh) * dw
                      + v10 * dh * (1.0f - dw)
                      + v11 * dh * dw;
            sout[c * KK + ph * AW + pw] = valid ? val : 0.0f;
        }
    }
    __syncthreads();
    float* ob = out + (size_t)r * C_ * KK;
    #pragma unroll 4
    for (int i = threadIdx.x; i < C_ * KK; i += 256) ob[i] = sout[i];
}

extern "C" void kernel_launch(void* const* d_in, const int* in_sizes, int n_in,
                              void* d_out, int out_size, void* d_ws, size_t ws_size,
                              hipStream_t stream) {
    const float* feat  = (const float*)d_in[0];
    const float* rois  = (const float*)d_in[1];
    const float* scale = (const float*)d_in[2];
    float* out = (float*)d_out;

    const int R = in_sizes[1] / 5;                 // 2000
    const int N = in_sizes[0] / (C_ * H_ * W_);    // 2
    const size_t need = (size_t)N * C_ * H_ * W_ * sizeof(unsigned short);

    if (ws_size >= need) {
        unsigned short* tf = (unsigned short*)d_ws;
        dim3 tb(256);
        // x-dim replicated REP times (folded inside kernel) -> one big dispatch
        dim3 tg((H_ * W_) / 64 * REP, C_ / 128, N);
        hipLaunchKernelGGL(transpose_nchw_nhwc_bf16, tg, tb, 0, stream, feat, tf);
        // y-dim replicas ignored in-kernel (identical writes)
        hipLaunchKernelGGL(roialign_nhwc_bf16, dim3(R, REP), dim3(512), 0, stream,
                           tf, rois, scale, out);
    } else {
        hipLaunchKernelGGL(roialign_nchw, dim3(R), dim3(256), 0, stream,
                           feat, rois, scale, out);
    }
}

// Round 7
// 94.434 us; speedup vs baseline: 2.2001x; 2.2001x over previous
//
#include <hip/hip_runtime.h>

// RoIAlign (aligned-corner variant), fixed shape:
//   features: (N=2, C=256, H=200, W=304) f32 NCHW, rois: (R,5) f32, scale f32
//   out: (R, 256, 7, 7) f32
// Pipeline: NCHW f32 -> NHWC f16 transpose (ws), then coalesced gather with
// f16 LDS staging in [c][k] layout (conflict-managed).
#define C_ 256
#define H_ 200
#define W_ 304
#define AH 7
#define AW 7
#define KK 49
#define PADK 66  // halves per LDS row (132 B); word-stride 33 (odd) -> 2-way copy-out reads

typedef float f32x4  __attribute__((ext_vector_type(4)));
typedef float f32x4u __attribute__((ext_vector_type(4), aligned(4)));  // align-4 vec store

__device__ __forceinline__ float h2f(unsigned short s) {
    _Float16 h; __builtin_memcpy(&h, &s, 2); return (float)h;
}
__device__ __forceinline__ unsigned short f2h(float f) {
    _Float16 h = (_Float16)f; unsigned short s; __builtin_memcpy(&s, &h, 2); return s;
}

// ---------- Kernel 1: NCHW f32 -> NHWC f16 (at HBM roofline, unchanged structure) ----------
__global__ __launch_bounds__(256) void transpose_nchw_nhwc_f16(
    const float* __restrict__ in, unsigned short* __restrict__ out) {
    __shared__ unsigned int tile[128][34];  // [ch][px-pair], 17408 B
    const int HW = H_ * W_;
    const int n  = blockIdx.z;
    const int p0 = blockIdx.x * 64;
    const int c0 = blockIdx.y * 128;
    const float* inb = in + (size_t)n * C_ * HW;
    unsigned short* outb = out + (size_t)n * HW * C_;

    {   // load: lanes walk pixel-quads, convert f32->f16 before LDS
        const int q  = threadIdx.x & 15;
        const int r0 = threadIdx.x >> 4;
        #pragma unroll
        for (int i = 0; i < 8; ++i) {
            const int c = r0 + 16 * i;
            const f32x4 v = __builtin_nontemporal_load(
                (const f32x4*)&inb[(size_t)(c0 + c) * HW + p0 + 4 * q]);
            const unsigned int ulo = (unsigned)f2h(v.x) | ((unsigned)f2h(v.y) << 16);
            const unsigned int uhi = (unsigned)f2h(v.z) | ((unsigned)f2h(v.w) << 16);
            *(uint2*)&tile[c][2 * q] = make_uint2(ulo, uhi);
        }
    }
    __syncthreads();
    {   // store: repack pixel-pairs -> channel-contiguous ushort8 (16B/lane)
        const int pp0 = threadIdx.x & 15;
        const int cq  = threadIdx.x >> 4;
        #pragma unroll
        for (int i = 0; i < 2; ++i) {
            const int pp = pp0 + 16 * i;
            unsigned int u[8];
            #pragma unroll
            for (int jj = 0; jj < 8; ++jj) u[jj] = tile[8 * cq + jj][pp];
            unsigned int pe[4], po[4];
            #pragma unroll
            for (int k = 0; k < 4; ++k) {
                pe[k] = (u[2 * k] & 0xFFFFu) | (u[2 * k + 1] << 16);
                po[k] = (u[2 * k] >> 16) | (u[2 * k + 1] & 0xFFFF0000u);
            }
            unsigned short* oA = &outb[(size_t)(p0 + 2 * pp) * C_ + c0 + 8 * cq];
            unsigned short* oB = oA + C_;
            *(uint4*)oA = make_uint4(pe[0], pe[1], pe[2], pe[3]);
            *(uint4*)oB = make_uint4(po[0], po[1], po[2], po[3]);
        }
    }
}

// ---------- sample one (roi, point) across 4 channels ----------
__device__ __forceinline__ void samp(
    const unsigned short* __restrict__ fb, int k,
    float y1, float x1, float bin_h, float bin_w, int c4, float* o) {
    const int ph = k / AW;
    const int pw = k - ph * AW;
    const float h  = y1 + (float)ph * bin_h;
    const float w  = x1 + (float)pw * bin_w;
    const float hs = fminf(fmaxf(floorf(h), 0.0f), (float)(H_ - 2));
    const float ws = fminf(fmaxf(floorf(w), 0.0f), (float)(W_ - 2));
    const float dh = h - hs;
    const float dw = w - ws;
    const int   yi = (int)hs;
    const int   xi = (int)ws;
    const bool  valid = (h >= 0.0f) && (h < (float)H_) &&
                        (w >= 0.0f) && (w < (float)W_);
    const unsigned short* p = fb + ((size_t)yi * W_ + xi) * C_ + c4;
    const ushort4 a00 = *(const ushort4*)p;
    const ushort4 a01 = *(const ushort4*)(p + C_);
    const ushort4 a10 = *(const ushort4*)(p + (size_t)W_ * C_);
    const ushort4 a11 = *(const ushort4*)(p + (size_t)W_ * C_ + C_);
    const float w00 = (1.0f - dh) * (1.0f - dw);
    const float w01 = (1.0f - dh) * dw;
    const float w10 = dh * (1.0f - dw);
    const float w11 = dh * dw;
    o[0] = h2f(a00.x) * w00 + h2f(a01.x) * w01 + h2f(a10.x) * w10 + h2f(a11.x) * w11;
    o[1] = h2f(a00.y) * w00 + h2f(a01.y) * w01 + h2f(a10.y) * w10 + h2f(a11.y) * w11;
    o[2] = h2f(a00.z) * w00 + h2f(a01.z) * w01 + h2f(a10.z) * w10 + h2f(a11.z) * w11;
    o[3] = h2f(a00.w) * w00 + h2f(a01.w) * w01 + h2f(a10.w) * w10 + h2f(a11.w) * w11;
    if (!valid) { o[0] = 0.0f; o[1] = 0.0f; o[2] = 0.0f; o[3] = 0.0f; }
}

// ---------- Kernel 2: gather from NHWC f16, f16 LDS staging [c][k] ----------
// 512 thr = 8 waves per ROI. Wave w: point-pairs kp in [3w, 3w+3) (k=2kp,2kp+1);
// wave 7 also does k=48. Lane owns 4 channels (ushort4 8B corner loads).
// LDS rows [c][PADK] halves; pair-packed u32 writes (8-way, 12/thread);
// copy-out u32 reads (2-way, free) -> f32 -> two 16B align-4 nontemporal stores.
__global__ __launch_bounds__(512, 6) void roialign_nhwc_f16(
    const unsigned short* __restrict__ tf, const float* __restrict__ rois,
    const float* __restrict__ scale_ptr, float* __restrict__ out) {
    __shared__ unsigned short sh[C_ * PADK];  // 33792 B -> 4 blocks/CU, 32 waves/CU
    const int r    = blockIdx.x;
    const int wave = threadIdx.x >> 6;
    const int lane = threadIdx.x & 63;
    const int c4   = lane * 4;

    const float scale = scale_ptr[0];
    const float* roi = rois + (size_t)r * 5;
    const int   b  = (int)roi[0];
    const float x1 = roi[1] * scale;
    const float y1 = roi[2] * scale;
    const float x2 = roi[3] * scale;
    const float y2 = roi[4] * scale;
    const float roi_w = fmaxf(x2 - x1 + 1.0f, 0.0f);
    const float roi_h = fmaxf(y2 - y1 + 1.0f, 0.0f);
    const float bin_h = roi_h / (float)(AH - 1);
    const float bin_w = roi_w / (float)(AW - 1);
    const unsigned short* fb = tf + (size_t)b * (H_ * W_) * C_;

    for (int kp = 3 * wave; kp < 3 * wave + 3; ++kp) {
        const int kA = 2 * kp;
        float vA[4], vB[4];
        samp(fb, kA,     y1, x1, bin_h, bin_w, c4, vA);
        samp(fb, kA + 1, y1, x1, bin_h, bin_w, c4, vB);
        #pragma unroll
        for (int j = 0; j < 4; ++j) {
            const unsigned int u = (unsigned)f2h(vA[j]) | ((unsigned)f2h(vB[j]) << 16);
            *(unsigned int*)&sh[(c4 + j) * PADK + kA] = u;
        }
    }
    if (wave == 7) {
        float v[4];
        samp(fb, 48, y1, x1, bin_h, bin_w, c4, v);
        #pragma unroll
        for (int j = 0; j < 4; ++j) sh[(c4 + j) * PADK + 48] = f2h(v[j]);
    }
    __syncthreads();

    const int j  = threadIdx.x & 7;   // k-octet 0..6 used
    const int cs = threadIdx.x >> 3;  // 0..63
    float* ob = out + (size_t)r * (C_ * KK);
    if (j < 7) {
        #pragma unroll
        for (int it = 0; it < 4; ++it) {
            const int c = cs + 64 * it;
            const unsigned short* row = &sh[c * PADK + 8 * j];
            float f[8];
            #pragma unroll
            for (int e = 0; e < 4; ++e) {
                const unsigned int u = *(const unsigned int*)&row[2 * e];
                f[2 * e]     = h2f((unsigned short)(u & 0xFFFFu));
                f[2 * e + 1] = h2f((unsigned short)(u >> 16));
            }
            float* dst = &ob[c * KK + 8 * j];
            if (j < 6) {
                f32x4u a = { f[0], f[1], f[2], f[3] };
                f32x4u bb = { f[4], f[5], f[6], f[7] };
                __builtin_nontemporal_store(a, (f32x4u*)dst);
                __builtin_nontemporal_store(bb, (f32x4u*)(dst + 4));
            } else {
                __builtin_nontemporal_store(f[0], dst);  // k=48 only
            }
        }
    }
}

// ---------- Fallback: direct NCHW gather (if ws too small) ----------
__global__ __launch_bounds__(256) void roialign_nchw(
    const float* __restrict__ feat, const float* __restrict__ rois,
    const float* __restrict__ scale_ptr, float* __restrict__ out) {
    __shared__ float sout[C_ * KK];
    const int r = blockIdx.x;
    const int c = threadIdx.x;
    const float scale = scale_ptr[0];
    const float* roi = rois + (size_t)r * 5;
    const int   b  = (int)roi[0];
    const float x1 = roi[1] * scale;
    const float y1 = roi[2] * scale;
    const float x2 = roi[3] * scale;
    const float y2 = roi[4] * scale;
    const float roi_w = fmaxf(x2 - x1 + 1.0f, 0.0f);
    const float roi_h = fmaxf(y2 - y1 + 1.0f, 0.0f);
    const float bin_h = roi_h / (float)(AH - 1);
    const float bin_w = roi_w / (float)(AW - 1);
    const float* fb = feat + ((size_t)b * C_ + c) * (H_ * W_);

    for (int ph = 0; ph < AH; ++ph) {
        const float h  = y1 + (float)ph * bin_h;
        const float hs = fminf(fmaxf(floorf(h), 0.0f), (float)(H_ - 2));
        const float dh = h - hs;
        const int   yi = (int)hs;
        const bool  vh = (h >= 0.0f) && (h < (float)H_);
        #pragma unroll
        for (int pw = 0; pw < AW; ++pw) {
            const float w  = x1 + (float)pw * bin_w;
            const float ws = fminf(fmaxf(floorf(w), 0.0f), (float)(W_ - 2));
            const float dw = w - ws;
            const int   xi = (int)ws;
            const bool  valid = vh && (w >= 0.0f) && (w < (float)W_);
            const float v00 = fb[(size_t)yi * W_ + xi];
            const float v01 = fb[(size_t)yi * W_ + xi + 1];
            const float v10 = fb[(size_t)(yi + 1) * W_ + xi];
            const float v11 = fb[(size_t)(yi + 1) * W_ + xi + 1];
            float val = v00 * (1.0f - dh) * (1.0f - dw)
                      + v01 * (1.0f - dh) * dw
                      + v10 * dh * (1.0f - dw)
                      + v11 * dh * dw;
            sout[c * KK + ph * AW + pw] = valid ? val : 0.0f;
        }
    }
    __syncthreads();
    float* ob = out + (size_t)r * C_ * KK;
    #pragma unroll 4
    for (int i = threadIdx.x; i < C_ * KK; i += 256) ob[i] = sout[i];
}

extern "C" void kernel_launch(void* const* d_in, const int* in_sizes, int n_in,
                              void* d_out, int out_size, void* d_ws, size_t ws_size,
                              hipStream_t stream) {
    const float* feat  = (const float*)d_in[0];
    const float* rois  = (const float*)d_in[1];
    const float* scale = (const float*)d_in[2];
    float* out = (float*)d_out;

    const int R = in_sizes[1] / 5;                 // 2000
    const int N = in_sizes[0] / (C_ * H_ * W_);    // 2
    const size_t need = (size_t)N * C_ * H_ * W_ * sizeof(unsigned short);

    if (ws_size >= need) {
        unsigned short* tf = (unsigned short*)d_ws;
        dim3 tb(256);
        dim3 tg((H_ * W_) / 64, C_ / 128, N);      // 950 x 2 x 2
        hipLaunchKernelGGL(transpose_nchw_nhwc_f16, tg, tb, 0, stream, feat, tf);
        hipLaunchKernelGGL(roialign_nhwc_f16, dim3(R), dim3(512), 0, stream,
                           tf, rois, scale, out);
    } else {
        hipLaunchKernelGGL(roialign_nchw, dim3(R), dim3(256), 0, stream,
                           feat, rois, scale, out);
    }
}

// Round 8
// 78.970 us; speedup vs baseline: 2.6309x; 1.1958x over previous
//
#include <hip/hip_runtime.h>

// RoIAlign (aligned-corner variant), fixed shape:
//   features: (N=2, C=256, H=200, W=304) f32 NCHW, rois: (R,5) f32, scale f32
//   out: (R, 256, 7, 7) f32
// Pipeline: NCHW f32 -> NHWC f16 transpose (ws, HBM-roofline), then gather
// with packed-f16 LDS staging [k][131 u32] (25.7KB -> 4 blocks/CU).
#define C_ 256
#define H_ 200
#define W_ 304
#define AH 7
#define AW 7
#define KK 49
#define ROWU 131  // u32 per LDS row; stride 131 = 3 mod 32 -> conflict-free scalar copy-out

typedef float f32x4 __attribute__((ext_vector_type(4)));

__device__ __forceinline__ float h2f(unsigned short s) {
    _Float16 h; __builtin_memcpy(&h, &s, 2); return (float)h;
}
__device__ __forceinline__ unsigned short f2h(float f) {
    _Float16 h = (_Float16)f; unsigned short s; __builtin_memcpy(&s, &h, 2); return s;
}

// ---------- Kernel 1: NCHW f32 -> NHWC f16 (HBM roofline; unchanged) ----------
__global__ __launch_bounds__(256) void transpose_nchw_nhwc_f16(
    const float* __restrict__ in, unsigned short* __restrict__ out) {
    __shared__ unsigned int tile[128][34];  // [ch][px-pair], 17408 B
    const int HW = H_ * W_;
    const int n  = blockIdx.z;
    const int p0 = blockIdx.x * 64;
    const int c0 = blockIdx.y * 128;
    const float* inb = in + (size_t)n * C_ * HW;
    unsigned short* outb = out + (size_t)n * HW * C_;

    {   // load: lanes walk pixel-quads, convert f32->f16 before LDS
        const int q  = threadIdx.x & 15;
        const int r0 = threadIdx.x >> 4;
        #pragma unroll
        for (int i = 0; i < 8; ++i) {
            const int c = r0 + 16 * i;
            const f32x4 v = __builtin_nontemporal_load(
                (const f32x4*)&inb[(size_t)(c0 + c) * HW + p0 + 4 * q]);
            const unsigned int ulo = (unsigned)f2h(v.x) | ((unsigned)f2h(v.y) << 16);
            const unsigned int uhi = (unsigned)f2h(v.z) | ((unsigned)f2h(v.w) << 16);
            *(uint2*)&tile[c][2 * q] = make_uint2(ulo, uhi);
        }
    }
    __syncthreads();
    {   // store: repack pixel-pairs -> channel-contiguous ushort8 (16B/lane)
        const int pp0 = threadIdx.x & 15;
        const int cq  = threadIdx.x >> 4;
        #pragma unroll
        for (int i = 0; i < 2; ++i) {
            const int pp = pp0 + 16 * i;
            unsigned int u[8];
            #pragma unroll
            for (int jj = 0; jj < 8; ++jj) u[jj] = tile[8 * cq + jj][pp];
            unsigned int pe[4], po[4];
            #pragma unroll
            for (int k = 0; k < 4; ++k) {
                pe[k] = (u[2 * k] & 0xFFFFu) | (u[2 * k + 1] << 16);
                po[k] = (u[2 * k] >> 16) | (u[2 * k + 1] & 0xFFFF0000u);
            }
            unsigned short* oA = &outb[(size_t)(p0 + 2 * pp) * C_ + c0 + 8 * cq];
            unsigned short* oB = oA + C_;
            *(uint4*)oA = make_uint4(pe[0], pe[1], pe[2], pe[3]);
            *(uint4*)oB = make_uint4(po[0], po[1], po[2], po[3]);
        }
    }
}

// ---------- sample one (roi, point) across 4 channels ----------
__device__ __forceinline__ void samp(
    const unsigned short* __restrict__ fb, int k,
    float y1, float x1, float bin_h, float bin_w, int c4, float* o) {
    const int ph = k / AW;
    const int pw = k - ph * AW;
    const float h  = y1 + (float)ph * bin_h;
    const float w  = x1 + (float)pw * bin_w;
    const float hs = fminf(fmaxf(floorf(h), 0.0f), (float)(H_ - 2));
    const float ws = fminf(fmaxf(floorf(w), 0.0f), (float)(W_ - 2));
    const float dh = h - hs;
    const float dw = w - ws;
    const int   yi = (int)hs;
    const int   xi = (int)ws;
    const bool  valid = (h >= 0.0f) && (h < (float)H_) &&
                        (w >= 0.0f) && (w < (float)W_);
    const unsigned short* p = fb + ((size_t)yi * W_ + xi) * C_ + c4;
    const ushort4 a00 = *(const ushort4*)p;
    const ushort4 a01 = *(const ushort4*)(p + C_);
    const ushort4 a10 = *(const ushort4*)(p + (size_t)W_ * C_);
    const ushort4 a11 = *(const ushort4*)(p + (size_t)W_ * C_ + C_);
    const float w00 = (1.0f - dh) * (1.0f - dw);
    const float w01 = (1.0f - dh) * dw;
    const float w10 = dh * (1.0f - dw);
    const float w11 = dh * dw;
    o[0] = h2f(a00.x) * w00 + h2f(a01.x) * w01 + h2f(a10.x) * w10 + h2f(a11.x) * w11;
    o[1] = h2f(a00.y) * w00 + h2f(a01.y) * w01 + h2f(a10.y) * w10 + h2f(a11.y) * w11;
    o[2] = h2f(a00.z) * w00 + h2f(a01.z) * w01 + h2f(a10.z) * w10 + h2f(a11.z) * w11;
    o[3] = h2f(a00.w) * w00 + h2f(a01.w) * w01 + h2f(a10.w) * w10 + h2f(a11.w) * w11;
    if (!valid) { o[0] = 0.0f; o[1] = 0.0f; o[2] = 0.0f; o[3] = 0.0f; }
}

// ---------- Kernel 2: gather from NHWC f16, packed-f16 LDS staging ----------
// 512 thr = 8 waves per ROI. Wave w: points k = w, w+8, ... (R5 structure).
// Lane owns 4 channels (ushort4 8B corner loads, 512B/corner/wave coalesced).
// LDS: u32 shu[49][ROWU]; row k holds 128 c-pairs at [2*lane], [2*lane+1].
// Copy-out: scalar flat (f = c*49+k), addr k*131+(c>>1): stride 3 mod 32 ->
// conflict-free; scalar nontemporal dword stores (256B/wave-instr).
__global__ __launch_bounds__(512) void roialign_nhwc_f16(
    const unsigned short* __restrict__ tf, const float* __restrict__ rois,
    const float* __restrict__ scale_ptr, float* __restrict__ out) {
    __shared__ unsigned int shu[KK * ROWU];  // 25676 B -> 4 blocks/CU (thread-cap)
    const int r    = blockIdx.x;
    const int wave = threadIdx.x >> 6;
    const int lane = threadIdx.x & 63;
    const int c4   = lane * 4;

    const float scale = scale_ptr[0];
    const float* roi = rois + (size_t)r * 5;
    const int   b  = (int)roi[0];
    const float x1 = roi[1] * scale;
    const float y1 = roi[2] * scale;
    const float x2 = roi[3] * scale;
    const float y2 = roi[4] * scale;
    const float roi_w = fmaxf(x2 - x1 + 1.0f, 0.0f);
    const float roi_h = fmaxf(y2 - y1 + 1.0f, 0.0f);
    const float bin_h = roi_h / (float)(AH - 1);
    const float bin_w = roi_w / (float)(AW - 1);
    const unsigned short* fb = tf + (size_t)b * (H_ * W_) * C_;

    #pragma unroll 2
    for (int k = wave; k < KK; k += 8) {
        float v[4];
        samp(fb, k, y1, x1, bin_h, bin_w, c4, v);
        const unsigned int u0 = (unsigned)f2h(v[0]) | ((unsigned)f2h(v[1]) << 16);
        const unsigned int u1 = (unsigned)f2h(v[2]) | ((unsigned)f2h(v[3]) << 16);
        shu[k * ROWU + 2 * lane]     = u0;
        shu[k * ROWU + 2 * lane + 1] = u1;
    }
    __syncthreads();

    float* ob = out + (size_t)r * (C_ * KK);
    #pragma unroll
    for (int i = 0; i < 25; ++i) {
        const int f = threadIdx.x + 512 * i;
        if (i < 24 || f < C_ * KK) {
            const int c = f / KK;          // magic-mul
            const int k = f - c * KK;
            const unsigned int u = shu[k * ROWU + (c >> 1)];
            const unsigned short hv = (c & 1) ? (unsigned short)(u >> 16)
                                              : (unsigned short)(u & 0xFFFFu);
            __builtin_nontemporal_store(h2f(hv), &ob[f]);
        }
    }
}

// ---------- Fallback: direct NCHW gather (if ws too small) ----------
__global__ __launch_bounds__(256) void roialign_nchw(
    const float* __restrict__ feat, const float* __restrict__ rois,
    const float* __restrict__ scale_ptr, float* __restrict__ out) {
    __shared__ float sout[C_ * KK];
    const int r = blockIdx.x;
    const int c = threadIdx.x;
    const float scale = scale_ptr[0];
    const float* roi = rois + (size_t)r * 5;
    const int   b  = (int)roi[0];
    const float x1 = roi[1] * scale;
    const float y1 = roi[2] * scale;
    const float x2 = roi[3] * scale;
    const float y2 = roi[4] * scale;
    const float roi_w = fmaxf(x2 - x1 + 1.0f, 0.0f);
    const float roi_h = fmaxf(y2 - y1 + 1.0f, 0.0f);
    const float bin_h = roi_h / (float)(AH - 1);
    const float bin_w = roi_w / (float)(AW - 1);
    const float* fb = feat + ((size_t)b * C_ + c) * (H_ * W_);

    for (int ph = 0; ph < AH; ++ph) {
        const float h  = y1 + (float)ph * bin_h;
        const float hs = fminf(fmaxf(floorf(h), 0.0f), (float)(H_ - 2));
        const float dh = h - hs;
        const int   yi = (int)hs;
        const bool  vh = (h >= 0.0f) && (h < (float)H_);
        #pragma unroll
        for (int pw = 0; pw < AW; ++pw) {
            const float w  = x1 + (float)pw * bin_w;
            const float ws = fminf(fmaxf(floorf(w), 0.0f), (float)(W_ - 2));
            const float dw = w - ws;
            const int   xi = (int)ws;
            const bool  valid = vh && (w >= 0.0f) && (w < (float)W_);
            const float v00 = fb[(size_t)yi * W_ + xi];
            const float v01 = fb[(size_t)yi * W_ + xi + 1];
            const float v10 = fb[(size_t)(yi + 1) * W_ + xi];
            const float v11 = fb[(size_t)(yi + 1) * W_ + xi + 1];
            float val = v00 * (1.0f - dh) * (1.0f - dw)
                      + v01 * (1.0f - dh) * dw
                      + v10 * dh * (1.0f - dw)
                      + v11 * dh * dw;
            sout[c * KK + ph * AW + pw] = valid ? val : 0.0f;
        }
    }
    __syncthreads();
    float* ob = out + (size_t)r * C_ * KK;
    #pragma unroll 4
    for (int i = threadIdx.x; i < C_ * KK; i += 256) ob[i] = sout[i];
}

extern "C" void kernel_launch(void* const* d_in, const int* in_sizes, int n_in,
                              void* d_out, int out_size, void* d_ws, size_t ws_size,
                              hipStream_t stream) {
    const float* feat  = (const float*)d_in[0];
    const float* rois  = (const float*)d_in[1];
    const float* scale = (const float*)d_in[2];
    float* out = (float*)d_out;

    const int R = in_sizes[1] / 5;                 // 2000
    const int N = in_sizes[0] / (C_ * H_ * W_);    // 2
    const size_t need = (size_t)N * C_ * H_ * W_ * sizeof(unsigned short);

    if (ws_size >= need) {
        unsigned short* tf = (unsigned short*)d_ws;
        dim3 tb(256);
        dim3 tg((H_ * W_) / 64, C_ / 128, N);      // 950 x 2 x 2
        hipLaunchKernelGGL(transpose_nchw_nhwc_f16, tg, tb, 0, stream, feat, tf);
        hipLaunchKernelGGL(roialign_nhwc_f16, dim3(R), dim3(512), 0, stream,
                           tf, rois, scale, out);
    } else {
        hipLaunchKernelGGL(roialign_nchw, dim3(R), dim3(256), 0, stream,
                           feat, rois, scale, out);
    }
}